// Round 13
// baseline (80.135 us; speedup 1.0000x reference)
//
#include <hip/hip_runtime.h>

#define TT 32
#define EMB 256
#define HEAD 64
#define NI 8   // items per wave; grid = 8192/(4*NI) = 256 = one block per CU

typedef __attribute__((ext_vector_type(8)))  short    bf16x8;
typedef __attribute__((ext_vector_type(16))) float    f32x16;
typedef __attribute__((ext_vector_type(4)))  float    f32x4;
typedef __attribute__((ext_vector_type(4)))  unsigned uint4v;

__device__ __forceinline__ unsigned pk2(float a, float b) {  // lo=a, hi=b (RNE)
  unsigned r;
  asm("v_cvt_pk_bf16_f32 %0, %1, %2" : "=v"(r) : "v"(a), "v"(b));
  return r;
}
__device__ __forceinline__ void plswap(unsigned a, unsigned b,
                                       unsigned& x, unsigned& y) {
  auto r = __builtin_amdgcn_permlane32_swap(a, b, false, false);
  x = r[0]; y = r[1];
}

// Single fused kernel (R12 base, verified 62.7us; delta: weights staged
// in-kernel from global W — removes the prep_weights launch + execution).
// sW[n][k] = W_{n/64}[k][n%64] bf16, swizzled u16 idx = n*256 + (k^((n&7)<<3)).
// No inline-asm waitcnt anywhere: compiler owns all load->use ordering.
__global__ __launch_bounds__(256, 1)
void attn_kernel(const float* __restrict__ X,
                 const float* __restrict__ Wq,
                 const float* __restrict__ Wk,
                 const float* __restrict__ Wv,
                 const float* __restrict__ bq,
                 const float* __restrict__ bv,
                 float* __restrict__ out) {
  __shared__ unsigned short sW[192 * 256];   // 96 KB, swizzled layout

  const int tid  = threadIdx.x;
  const int wid  = tid >> 6;
  const int lane = tid & 63;
  const int lo   = lane & 31;   // MFMA tile row/col
  const int hi   = lane >> 5;   // k-half selector

  const long itemBase = (long)blockIdx.x * (4 * NI) + wid * NI;
  const float* Xb0 = X + itemBase * (TT * EMB);
  float* ob0 = out + itemBase * (TT * HEAD);

  const float* XpBase = Xb0 + lo * EMB + hi * 8;

  // chunk c of item jj: 8 x dwordx4 into F[c*8 .. c*8+7]
#define ISSUE_CHUNK(jj, c)                                                   \
  do {                                                                       \
    const float* Xp_ = XpBase + (jj) * (TT * EMB);                           \
    _Pragma("unroll")                                                        \
    for (int i_ = (c) * 8; i_ < (c) * 8 + 8; ++i_)                           \
      F[i_] = *(const f32x4*)(Xp_ + (i_ >> 1) * 16 + (i_ & 1) * 4);          \
  } while (0)

  f32x4 F[32];
  ISSUE_CHUNK(0, 0); ISSUE_CHUNK(0, 1); ISSUE_CHUNK(0, 2); ISSUE_CHUNK(0, 3);

  // ---- stage weights -> LDS (transpose + cvt in-flight; L2-resident W).
  // 96 even-k pairs per thread; XOR swizzle affects k bits 3..5 only, so
  // pairs stay contiguous -> b32 writes, b128 reads unchanged.
  {
#pragma unroll 8
    for (int p = 0; p < 96; ++p) {
      int gp = p * 256 + tid;          // global pair index
      int n  = gp >> 7;                // 0..191
      int k  = (gp & 127) * 2;         // even k
      const float* W = (n < 64) ? Wq : (n < 128) ? Wk : Wv;
      int col = n & 63;
      float w0 = W[k * 64 + col];
      float w1 = W[(k + 1) * 64 + col];
      *(unsigned*)&sW[n * 256 + (k ^ ((n & 7) << 3))] = pk2(w0, w1);
    }
  }

  // ---- loop-invariant bias regs ----
  // bq as Q-acc init (C layout: col t=lo, row h=(r&3)+8*(r>>2)+4*hi+32nt)
  f32x16 bQ2[2];
#pragma unroll
  for (int nt = 0; nt < 2; ++nt)
#pragma unroll
    for (int g = 0; g < 4; ++g) {
      f32x4 t = *(const f32x4*)(bq + nt * 32 + g * 8 + hi * 4);
#pragma unroll
      for (int q = 0; q < 4; ++q) bQ2[nt][g * 4 + q] = t[q];
    }
  // bv folds into PV accumulator init (softmax rows sum to 1); bk cancels.
  const float bv0 = bv[lo], bv1 = bv[32 + lo];

  __syncthreads();    // sW published; F[item0] ordering handled by compiler

#pragma unroll 1
  for (int j = 0; j < NI; ++j) {
    // ---- cvt F -> bf16 fragments for item j ----
    uint4v Bf[16];
#pragma unroll
    for (int kk = 0; kk < 16; ++kk) {
      Bf[kk][0] = pk2(F[kk * 2][0],     F[kk * 2][1]);
      Bf[kk][1] = pk2(F[kk * 2][2],     F[kk * 2][3]);
      Bf[kk][2] = pk2(F[kk * 2 + 1][0], F[kk * 2 + 1][1]);
      Bf[kk][3] = pk2(F[kk * 2 + 1][2], F[kk * 2 + 1][3]);
    }
    __builtin_amdgcn_sched_barrier(0);

    // ---- projection: QT,KT = W^T·X^T ; V = X·Wv  (weights from LDS);
    //      next-item loads issued in 4 chunks at kk = 0,4,8,12 ----
    f32x16 aQ[2], aK[2], aV[2];
    aQ[0] = bQ2[0]; aQ[1] = bQ2[1];
#pragma unroll
    for (int nt = 0; nt < 2; ++nt)
#pragma unroll
      for (int r = 0; r < 16; ++r) { aK[nt][r] = 0.0f; aV[nt][r] = 0.0f; }

#pragma unroll
    for (int kk = 0; kk < 16; ++kk) {
      if ((kk & 3) == 0 && j + 1 < NI) { ISSUE_CHUNK(j + 1, kk >> 2); }
      bf16x8 a = __builtin_bit_cast(bf16x8, Bf[kk]);
      const int csw = (kk * 16 + hi * 8) ^ ((lo & 7) << 3);  // swizzled u16 col
#pragma unroll
      for (int nt = 0; nt < 2; ++nt) {
        bf16x8 wq = *(const bf16x8*)&sW[(nt * 32 + lo) * 256 + csw];
        aQ[nt] = __builtin_amdgcn_mfma_f32_32x32x16_bf16(wq, a, aQ[nt], 0, 0, 0);
        bf16x8 wk = *(const bf16x8*)&sW[(64 + nt * 32 + lo) * 256 + csw];
        aK[nt] = __builtin_amdgcn_mfma_f32_32x32x16_bf16(wk, a, aK[nt], 0, 0, 0);
        bf16x8 wv = *(const bf16x8*)&sW[(128 + nt * 32 + lo) * 256 + csw];
        aV[nt] = __builtin_amdgcn_mfma_f32_32x32x16_bf16(a, wv, aV[nt], 0, 0, 0);
      }
    }

    // ---- pack as bf16 pairs along q: [nt][g][pair] ----
    unsigned Qp[2][4][2], Kp[2][4][2], Vp[2][4][2];
#pragma unroll
    for (int nt = 0; nt < 2; ++nt)
#pragma unroll
      for (int g = 0; g < 4; ++g) {
        Qp[nt][g][0] = pk2(aQ[nt][g * 4 + 0], aQ[nt][g * 4 + 1]);
        Qp[nt][g][1] = pk2(aQ[nt][g * 4 + 2], aQ[nt][g * 4 + 3]);
        Kp[nt][g][0] = pk2(aK[nt][g * 4 + 0], aK[nt][g * 4 + 1]);
        Kp[nt][g][1] = pk2(aK[nt][g * 4 + 2], aK[nt][g * 4 + 3]);
        Vp[nt][g][0] = pk2(aV[nt][g * 4 + 0], aV[nt][g * 4 + 1]);
        Vp[nt][g][1] = pk2(aV[nt][g * 4 + 2], aV[nt][g * 4 + 3]);
      }

    // ---- QK^T (swapped): weiT = K · Q^T ----
    f32x16 wei;
#pragma unroll
    for (int r = 0; r < 16; ++r) wei[r] = 0.0f;
#pragma unroll
    for (int kk = 0; kk < 4; ++kk) {
      const int nt = kk >> 1, g0 = (2 * kk) & 3, g1 = (2 * kk + 1) & 3;
      unsigned k0w, k1w, k2w, k3w, q0w, q1w, q2w, q3w;
      plswap(Kp[nt][g0][0], Kp[nt][g1][0], k0w, k2w);
      plswap(Kp[nt][g0][1], Kp[nt][g1][1], k1w, k3w);
      plswap(Qp[nt][g0][0], Qp[nt][g1][0], q0w, q2w);
      plswap(Qp[nt][g0][1], Qp[nt][g1][1], q1w, q3w);
      uint4v kw = { k0w, k1w, k2w, k3w };
      uint4v qw = { q0w, q1w, q2w, q3w };
      wei = __builtin_amdgcn_mfma_f32_32x32x16_bf16(
          __builtin_bit_cast(bf16x8, kw), __builtin_bit_cast(bf16x8, qw), wei, 0, 0, 0);
    }

    // ---- softmax over s for query t=lo (lane pairs l, l^32) ----
    float pv[16];
    float m = -3.0e38f;
#pragma unroll
    for (int r = 0; r < 16; ++r) {
      int s = (r & 3) + 8 * (r >> 2) + 4 * hi;
      float v = (s <= lo) ? wei[r] * 0.125f : -__builtin_inff();
      pv[r] = v;
      m = fmaxf(m, v);
    }
    m = fmaxf(m, __shfl_xor(m, 32));
    float sum = 0.0f;
#pragma unroll
    for (int r = 0; r < 16; ++r) {
      float e = __expf(pv[r] - m);
      pv[r] = e;
      sum += e;
    }
    sum += __shfl_xor(sum, 32);
    const float inv = 1.0f / sum;

    unsigned Pp[4][2];
#pragma unroll
    for (int g = 0; g < 4; ++g) {
      Pp[g][0] = pk2(pv[g * 4 + 0] * inv, pv[g * 4 + 1] * inv);
      Pp[g][1] = pk2(pv[g * 4 + 2] * inv, pv[g * 4 + 3] * inv);
    }

    // ---- out = P · V  (+ bv via acc init; softmax row-sum = 1) ----
    f32x16 o[2];
#pragma unroll
    for (int r = 0; r < 16; ++r) { o[0][r] = bv0; o[1][r] = bv1; }

#pragma unroll
    for (int kk = 0; kk < 2; ++kk) {
      const int g0 = 2 * kk, g1 = 2 * kk + 1;
      unsigned p0w, p1w, p2w, p3w;
      plswap(Pp[g0][0], Pp[g1][0], p0w, p2w);
      plswap(Pp[g0][1], Pp[g1][1], p1w, p3w);
      uint4v pw = { p0w, p1w, p2w, p3w };
      bf16x8 pa = __builtin_bit_cast(bf16x8, pw);
#pragma unroll
      for (int nt = 0; nt < 2; ++nt) {
        unsigned v0w, v1w, v2w, v3w;
        plswap(Vp[nt][g0][0], Vp[nt][g1][0], v0w, v2w);
        plswap(Vp[nt][g0][1], Vp[nt][g1][1], v1w, v3w);
        uint4v vw = { v0w, v1w, v2w, v3w };
        o[nt] = __builtin_amdgcn_mfma_f32_32x32x16_bf16(
            pa, __builtin_bit_cast(bf16x8, vw), o[nt], 0, 0, 0);
      }
    }

    // ---- stores (nontemporal; 2x128B segments per instr) ----
    float* ob = ob0 + j * (TT * HEAD);
#pragma unroll
    for (int nt = 0; nt < 2; ++nt) {
      int h = nt * 32 + lo;
#pragma unroll
      for (int r = 0; r < 16; ++r) {
        int row = (r & 3) + 8 * (r >> 2) + 4 * hi;
        __builtin_nontemporal_store(o[nt][r], &ob[row * HEAD + h]);
      }
    }
  }
#undef ISSUE_CHUNK
}

extern "C" void kernel_launch(void* const* d_in, const int* in_sizes, int n_in,
                              void* d_out, int out_size, void* d_ws, size_t ws_size,
                              hipStream_t stream) {
  const float* X  = (const float*)d_in[0];
  const float* Wq = (const float*)d_in[1];
  const float* bq = (const float*)d_in[2];
  const float* Wk = (const float*)d_in[3];
  const float* Wv = (const float*)d_in[5];
  const float* bv = (const float*)d_in[6];
  float* out = (float*)d_out;

  const int B = in_sizes[0] / (TT * EMB);  // 8192

  attn_kernel<<<B / (4 * NI), 256, 0, stream>>>(X, Wq, Wk, Wv, bq, bv, out);
}

// Round 14
// 63.967 us; speedup vs baseline: 1.2528x; 1.2528x over previous
//
#include <hip/hip_runtime.h>

#define TT 32
#define EMB 256
#define HEAD 64
#define NI 8   // items per wave; grid = 8192/(4*NI) = 256 = one block per CU

typedef __attribute__((ext_vector_type(8)))  short    bf16x8;
typedef __attribute__((ext_vector_type(16))) float    f32x16;
typedef __attribute__((ext_vector_type(4)))  float    f32x4;
typedef __attribute__((ext_vector_type(4)))  unsigned uint4v;

__device__ __forceinline__ unsigned bfr(float f) {   // bf16 bits (RNE), low 16
  unsigned u = __builtin_bit_cast(unsigned, f);
  u += 0x7fffu + ((u >> 16) & 1u);
  return u >> 16;
}
__device__ __forceinline__ unsigned pk2(float a, float b) {  // lo=a, hi=b
  unsigned r;
  asm("v_cvt_pk_bf16_f32 %0, %1, %2" : "=v"(r) : "v"(a), "v"(b));
  return r;
}
__device__ __forceinline__ void plswap(unsigned a, unsigned b,
                                       unsigned& x, unsigned& y) {
  auto r = __builtin_amdgcn_permlane32_swap(a, b, false, false);
  x = r[0]; y = r[1];
}

// Wt[n][k] = W_{n/64}[k][n%64] bf16, stored SWIZZLED: u16 idx = n*256 + (k ^ ((n&7)<<3))
__global__ void prep_weights(const float* __restrict__ Wq,
                             const float* __restrict__ Wk,
                             const float* __restrict__ Wv,
                             unsigned short* __restrict__ Wt) {
  int idx = blockIdx.x * 256 + threadIdx.x;   // 192*256 total
  int n = idx >> 8, k = idx & 255;
  const float* W = (n < 64) ? Wq : (n < 128) ? Wk : Wv;
  Wt[n * 256 + (k ^ ((n & 7) << 3))] = (unsigned short)bfr(W[k * 64 + (n & 63)]);
}

// R12 verified best (62.7us): 4 waves/block, one block/CU, Wt staged once in
// LDS (96 KB); NI items per wave with next-item X loads issued in 4 chunks of
// 8 spread through the MFMA loop (kk=0,4,8,12) — keeps the VMEM request
// stream near 100% duty cycle. No inline-asm waitcnt anywhere: the compiler's
// waitcnt pass owns all load->use ordering (R11 lesson: it beats hand asm).
__global__ __launch_bounds__(256, 1)
void attn_kernel(const float* __restrict__ X,
                 const unsigned short* __restrict__ Wt,
                 const float* __restrict__ bq,
                 const float* __restrict__ bv,
                 float* __restrict__ out) {
  __shared__ unsigned short sW[192 * 256];   // 96 KB, swizzled layout

  const int tid  = threadIdx.x;
  const int wid  = tid >> 6;
  const int lane = tid & 63;
  const int lo   = lane & 31;   // MFMA tile row/col
  const int hi   = lane >> 5;   // k-half selector

  // ---- stage Wt -> LDS: linear 24 KB per wave (layout pre-swizzled) ----
  {
    const unsigned short* src = Wt + wid * 12288 + lane * 8;
#pragma unroll
    for (int i = 0; i < 24; ++i) {
      __builtin_amdgcn_global_load_lds(
          (const __attribute__((address_space(1))) void*)(src + i * 512),
          (__attribute__((address_space(3))) void*)(&sW[wid * 12288 + i * 512]),
          16, 0, 0);
    }
  }

  const long itemBase = (long)blockIdx.x * (4 * NI) + wid * NI;
  const float* Xb0 = X + itemBase * (TT * EMB);
  float* ob0 = out + itemBase * (TT * HEAD);

  // ---- loop-invariant bias regs ----
  // bq as Q-acc init (C layout: col t=lo, row h=(r&3)+8*(r>>2)+4*hi+32nt)
  f32x16 bQ2[2];
#pragma unroll
  for (int nt = 0; nt < 2; ++nt)
#pragma unroll
    for (int g = 0; g < 4; ++g) {
      f32x4 t = *(const f32x4*)(bq + nt * 32 + g * 8 + hi * 4);
#pragma unroll
      for (int q = 0; q < 4; ++q) bQ2[nt][g * 4 + q] = t[q];
    }
  // bv folds into PV accumulator init (softmax rows sum to 1); bk cancels.
  const float bv0 = bv[lo], bv1 = bv[32 + lo];

  const float* XpBase = Xb0 + lo * EMB + hi * 8;

  // chunk c of item jj: 8 x dwordx4 into F[c*8 .. c*8+7]
#define ISSUE_CHUNK(jj, c)                                                   \
  do {                                                                       \
    const float* Xp_ = XpBase + (jj) * (TT * EMB);                           \
    _Pragma("unroll")                                                        \
    for (int i_ = (c) * 8; i_ < (c) * 8 + 8; ++i_)                           \
      F[i_] = *(const f32x4*)(Xp_ + (i_ >> 1) * 16 + (i_ & 1) * 4);          \
  } while (0)

  f32x4 F[32];
  ISSUE_CHUNK(0, 0); ISSUE_CHUNK(0, 1); ISSUE_CHUNK(0, 2); ISSUE_CHUNK(0, 3);

  __syncthreads();    // drains vmcnt+lgkmcnt: sW and F[item0] both ready

#pragma unroll 1
  for (int j = 0; j < NI; ++j) {
    // ---- cvt F -> bf16 fragments for item j ----
    // (compiler inserts incremental vmcnt waits for F's loads as needed)
    uint4v Bf[16];
#pragma unroll
    for (int kk = 0; kk < 16; ++kk) {
      Bf[kk][0] = pk2(F[kk * 2][0],     F[kk * 2][1]);
      Bf[kk][1] = pk2(F[kk * 2][2],     F[kk * 2][3]);
      Bf[kk][2] = pk2(F[kk * 2 + 1][0], F[kk * 2 + 1][1]);
      Bf[kk][3] = pk2(F[kk * 2 + 1][2], F[kk * 2 + 1][3]);
    }
    __builtin_amdgcn_sched_barrier(0);

    // ---- projection: QT,KT = W^T·X^T ; V = X·Wv  (weights from LDS);
    //      next-item loads issued in 4 chunks at kk = 0,4,8,12 ----
    f32x16 aQ[2], aK[2], aV[2];
    aQ[0] = bQ2[0]; aQ[1] = bQ2[1];
#pragma unroll
    for (int nt = 0; nt < 2; ++nt)
#pragma unroll
      for (int r = 0; r < 16; ++r) { aK[nt][r] = 0.0f; aV[nt][r] = 0.0f; }

#pragma unroll
    for (int kk = 0; kk < 16; ++kk) {
      if ((kk & 3) == 0 && j + 1 < NI) { ISSUE_CHUNK(j + 1, kk >> 2); }
      bf16x8 a = __builtin_bit_cast(bf16x8, Bf[kk]);
      const int csw = (kk * 16 + hi * 8) ^ ((lo & 7) << 3);  // swizzled u16 col
#pragma unroll
      for (int nt = 0; nt < 2; ++nt) {
        bf16x8 wq = *(const bf16x8*)&sW[(nt * 32 + lo) * 256 + csw];
        aQ[nt] = __builtin_amdgcn_mfma_f32_32x32x16_bf16(wq, a, aQ[nt], 0, 0, 0);
        bf16x8 wk = *(const bf16x8*)&sW[(64 + nt * 32 + lo) * 256 + csw];
        aK[nt] = __builtin_amdgcn_mfma_f32_32x32x16_bf16(wk, a, aK[nt], 0, 0, 0);
        bf16x8 wv = *(const bf16x8*)&sW[(128 + nt * 32 + lo) * 256 + csw];
        aV[nt] = __builtin_amdgcn_mfma_f32_32x32x16_bf16(a, wv, aV[nt], 0, 0, 0);
      }
    }

    // ---- pack as bf16 pairs along q: [nt][g][pair] ----
    unsigned Qp[2][4][2], Kp[2][4][2], Vp[2][4][2];
#pragma unroll
    for (int nt = 0; nt < 2; ++nt)
#pragma unroll
      for (int g = 0; g < 4; ++g) {
        Qp[nt][g][0] = pk2(aQ[nt][g * 4 + 0], aQ[nt][g * 4 + 1]);
        Qp[nt][g][1] = pk2(aQ[nt][g * 4 + 2], aQ[nt][g * 4 + 3]);
        Kp[nt][g][0] = pk2(aK[nt][g * 4 + 0], aK[nt][g * 4 + 1]);
        Kp[nt][g][1] = pk2(aK[nt][g * 4 + 2], aK[nt][g * 4 + 3]);
        Vp[nt][g][0] = pk2(aV[nt][g * 4 + 0], aV[nt][g * 4 + 1]);
        Vp[nt][g][1] = pk2(aV[nt][g * 4 + 2], aV[nt][g * 4 + 3]);
      }

    // ---- QK^T (swapped): weiT = K · Q^T ----
    f32x16 wei;
#pragma unroll
    for (int r = 0; r < 16; ++r) wei[r] = 0.0f;
#pragma unroll
    for (int kk = 0; kk < 4; ++kk) {
      const int nt = kk >> 1, g0 = (2 * kk) & 3, g1 = (2 * kk + 1) & 3;
      unsigned k0w, k1w, k2w, k3w, q0w, q1w, q2w, q3w;
      plswap(Kp[nt][g0][0], Kp[nt][g1][0], k0w, k2w);
      plswap(Kp[nt][g0][1], Kp[nt][g1][1], k1w, k3w);
      plswap(Qp[nt][g0][0], Qp[nt][g1][0], q0w, q2w);
      plswap(Qp[nt][g0][1], Qp[nt][g1][1], q1w, q3w);
      uint4v kw = { k0w, k1w, k2w, k3w };
      uint4v qw = { q0w, q1w, q2w, q3w };
      wei = __builtin_amdgcn_mfma_f32_32x32x16_bf16(
          __builtin_bit_cast(bf16x8, kw), __builtin_bit_cast(bf16x8, qw), wei, 0, 0, 0);
    }

    // ---- softmax over s for query t=lo (lane pairs l, l^32) ----
    float pv[16];
    float m = -3.0e38f;
#pragma unroll
    for (int r = 0; r < 16; ++r) {
      int s = (r & 3) + 8 * (r >> 2) + 4 * hi;
      float v = (s <= lo) ? wei[r] * 0.125f : -__builtin_inff();
      pv[r] = v;
      m = fmaxf(m, v);
    }
    m = fmaxf(m, __shfl_xor(m, 32));
    float sum = 0.0f;
#pragma unroll
    for (int r = 0; r < 16; ++r) {
      float e = __expf(pv[r] - m);
      pv[r] = e;
      sum += e;
    }
    sum += __shfl_xor(sum, 32);
    const float inv = 1.0f / sum;

    unsigned Pp[4][2];
#pragma unroll
    for (int g = 0; g < 4; ++g) {
      Pp[g][0] = pk2(pv[g * 4 + 0] * inv, pv[g * 4 + 1] * inv);
      Pp[g][1] = pk2(pv[g * 4 + 2] * inv, pv[g * 4 + 3] * inv);
    }

    // ---- out = P · V  (+ bv via acc init; softmax row-sum = 1) ----
    f32x16 o[2];
#pragma unroll
    for (int r = 0; r < 16; ++r) { o[0][r] = bv0; o[1][r] = bv1; }

#pragma unroll
    for (int kk = 0; kk < 2; ++kk) {
      const int g0 = 2 * kk, g1 = 2 * kk + 1;
      unsigned p0w, p1w, p2w, p3w;
      plswap(Pp[g0][0], Pp[g1][0], p0w, p2w);
      plswap(Pp[g0][1], Pp[g1][1], p1w, p3w);
      uint4v pw = { p0w, p1w, p2w, p3w };
      bf16x8 pa = __builtin_bit_cast(bf16x8, pw);
#pragma unroll
      for (int nt = 0; nt < 2; ++nt) {
        unsigned v0w, v1w, v2w, v3w;
        plswap(Vp[nt][g0][0], Vp[nt][g1][0], v0w, v2w);
        plswap(Vp[nt][g0][1], Vp[nt][g1][1], v1w, v3w);
        uint4v vw = { v0w, v1w, v2w, v3w };
        o[nt] = __builtin_amdgcn_mfma_f32_32x32x16_bf16(
            pa, __builtin_bit_cast(bf16x8, vw), o[nt], 0, 0, 0);
      }
    }

    // ---- stores (nontemporal; 2x128B segments per instr) ----
    float* ob = ob0 + j * (TT * HEAD);
#pragma unroll
    for (int nt = 0; nt < 2; ++nt) {
      int h = nt * 32 + lo;
#pragma unroll
      for (int r = 0; r < 16; ++r) {
        int row = (r & 3) + 8 * (r >> 2) + 4 * hi;
        __builtin_nontemporal_store(o[nt][r], &ob[row * HEAD + h]);
      }
    }
  }
#undef ISSUE_CHUNK
}

extern "C" void kernel_launch(void* const* d_in, const int* in_sizes, int n_in,
                              void* d_out, int out_size, void* d_ws, size_t ws_size,
                              hipStream_t stream) {
  const float* X  = (const float*)d_in[0];
  const float* Wq = (const float*)d_in[1];
  const float* bq = (const float*)d_in[2];
  const float* Wk = (const float*)d_in[3];
  const float* bv = (const float*)d_in[6];
  const float* Wv = (const float*)d_in[5];
  float* out = (float*)d_out;
  unsigned short* Wt = (unsigned short*)d_ws;  // 192*256 bf16 = 96 KB scratch

  const int B = in_sizes[0] / (TT * EMB);  // 8192

  prep_weights<<<192, 256, 0, stream>>>(Wq, Wk, Wv, Wt);
  attn_kernel<<<B / (4 * NI), 256, 0, stream>>>(X, Wt, bq, bv, out);
}